// Round 1
// baseline (96.759 us; speedup 1.0000x reference)
//
#include <hip/hip_runtime.h>
#include <math.h>

#define NQ 8
#define NL 4
#define PI_HALF 1.57079632679489662f

// ---------------------------------------------------------------------------
// Complex 2x2 gate on an amplitude pair (a0, a1): new0 = m00*a0 + m01*a1,
// new1 = m10*a0 + m11*a1.
// ---------------------------------------------------------------------------
__device__ __forceinline__ void rot_pair(
    float m00r, float m00i, float m01r, float m01i,
    float m10r, float m10i, float m11r, float m11i,
    float& r0, float& i0, float& r1, float& i1) {
  float nr0 = m00r * r0 - m00i * i0 + m01r * r1 - m01i * i1;
  float ni0 = m00r * i0 + m00i * r0 + m01r * i1 + m01i * r1;
  float nr1 = m10r * r0 - m10i * i0 + m11r * r1 - m11i * i1;
  float ni1 = m10r * i0 + m10i * r0 + m11r * i1 + m11i * r1;
  r0 = nr0; i0 = ni0; r1 = nr1; i1 = ni1;
}

// ---------------------------------------------------------------------------
// Rot gate on wire W. Amplitude index i = lane + 64*k.
//   bit position of wire w in i is p = 7 - w.
//   W==0 -> k bit 1 (in-register pairs (0,2),(1,3))
//   W==1 -> k bit 0 (in-register pairs (0,1),(2,3))
//   W>=2 -> lane bit (7-W), partner via shfl_xor
// m points to 8 floats in LDS: m00r,m00i,m01r,m01i,m10r,m10i,m11r,m11i
// ---------------------------------------------------------------------------
template <int W>
__device__ __forceinline__ void apply_rot(float (&re)[4], float (&im)[4],
                                          const float* m, int lane) {
  float4 mA = *(const float4*)(m);      // m00r m00i m01r m01i
  float4 mB = *(const float4*)(m + 4);  // m10r m10i m11r m11i
  if constexpr (W == 0) {
    rot_pair(mA.x, mA.y, mA.z, mA.w, mB.x, mB.y, mB.z, mB.w,
             re[0], im[0], re[2], im[2]);
    rot_pair(mA.x, mA.y, mA.z, mA.w, mB.x, mB.y, mB.z, mB.w,
             re[1], im[1], re[3], im[3]);
  } else if constexpr (W == 1) {
    rot_pair(mA.x, mA.y, mA.z, mA.w, mB.x, mB.y, mB.z, mB.w,
             re[0], im[0], re[1], im[1]);
    rot_pair(mA.x, mA.y, mA.z, mA.w, mB.x, mB.y, mB.z, mB.w,
             re[2], im[2], re[3], im[3]);
  } else {
    constexpr int P = 7 - W;  // lane-bit position, 5..0
    const int bit = (lane >> P) & 1;
    // own coeff:    bit ? m11 : m00 ; partner coeff: bit ? m10 : m01
    float car = bit ? mB.z : mA.x;
    float cai = bit ? mB.w : mA.y;
    float cbr = bit ? mB.x : mA.z;
    float cbi = bit ? mB.y : mA.w;
#pragma unroll
    for (int k = 0; k < 4; ++k) {
      float pr = __shfl_xor(re[k], 1 << P, 64);
      float pi = __shfl_xor(im[k], 1 << P, 64);
      float orr = re[k], oii = im[k];
      re[k] = car * orr - cai * oii + cbr * pr - cbi * pi;
      im[k] = car * oii + cai * orr + cbr * pi + cbi * pr;
    }
  }
}

// ---------------------------------------------------------------------------
// CNOT(C, T): new[i] = bit_C(i) ? old[i ^ (1 << (7-T))] : old[i]
// ---------------------------------------------------------------------------
template <int C, int T>
__device__ __forceinline__ void apply_cnot(float (&re)[4], float (&im)[4],
                                           int lane) {
  if constexpr (C >= 2 && T >= 2) {
    constexpr int PC = 7 - C;
    constexpr int MT = 1 << (7 - T);
    const int cbit = (lane >> PC) & 1;
#pragma unroll
    for (int k = 0; k < 4; ++k) {
      float pr = __shfl_xor(re[k], MT, 64);
      float pi = __shfl_xor(im[k], MT, 64);
      re[k] = cbit ? pr : re[k];
      im[k] = cbit ? pi : im[k];
    }
  } else if constexpr (C >= 2) {  // T < 2: target in register index
    constexpr int KT = (T == 0) ? 2 : 1;
    const int cbit = (lane >> (7 - C)) & 1;
    float nr[4], ni[4];
#pragma unroll
    for (int k = 0; k < 4; ++k) {
      nr[k] = cbit ? re[k ^ KT] : re[k];
      ni[k] = cbit ? im[k ^ KT] : im[k];
    }
#pragma unroll
    for (int k = 0; k < 4; ++k) { re[k] = nr[k]; im[k] = ni[k]; }
  } else if constexpr (T >= 2) {  // C < 2: control in register index
    constexpr int KC = (C == 0) ? 2 : 1;
    constexpr int MT = 1 << (7 - T);
#pragma unroll
    for (int k = 0; k < 4; ++k) {
      if (k & KC) {  // compile-time after unroll; no divergence
        re[k] = __shfl_xor(re[k], MT, 64);
        im[k] = __shfl_xor(im[k], MT, 64);
      }
    }
  } else {  // both in register index: static register swap
    constexpr int KC = (C == 0) ? 2 : 1;
    constexpr int KT = (T == 0) ? 2 : 1;
    float tr = re[KC], ti = im[KC];
    re[KC] = re[KC | KT]; im[KC] = im[KC | KT];
    re[KC | KT] = tr;     im[KC | KT] = ti;
  }
}

// ---------------------------------------------------------------------------
// Fused kernel: 4 waves / block, one sample per wave.
// ---------------------------------------------------------------------------
__global__ __launch_bounds__(256) void hqc_kernel(
    const float* __restrict__ x,
    const float* __restrict__ w1, const float* __restrict__ b1,
    const float* __restrict__ w2, const float* __restrict__ b2,
    const float* __restrict__ w3, const float* __restrict__ b3,
    const float* __restrict__ qw,
    const float* __restrict__ wp1, const float* __restrict__ bp1,
    const float* __restrict__ wp2, const float* __restrict__ bp2,
    const float* __restrict__ wp3, const float* __restrict__ bp3,
    float* __restrict__ out, int B) {
  __shared__ __align__(16) float rotm[NL * NQ][8];
  __shared__ float bufA[4][64];
  __shared__ float bufB[4][64];

  const int tid = threadIdx.x;
  const int wid = tid >> 6;
  const int lane = tid & 63;
  const int s = blockIdx.x * 4 + wid;

  // --- Rot matrices (identical for all samples), once per block ---
  if (tid < NL * NQ) {
    float phi = qw[tid * 3 + 0];
    float th  = qw[tid * 3 + 1];
    float om  = qw[tid * 3 + 2];
    float st_, ct; sincosf(0.5f * th, &st_, &ct);
    float sa, ca;  sincosf(0.5f * (phi + om), &sa, &ca);
    float sb, cb;  sincosf(0.5f * (phi - om), &sb, &cb);
    rotm[tid][0] =  ca * ct;  rotm[tid][1] = -sa * ct;   // m00
    rotm[tid][2] = -cb * st_; rotm[tid][3] = -sb * st_;  // m01
    rotm[tid][4] =  cb * st_; rotm[tid][5] = -sb * st_;  // m10
    rotm[tid][6] =  ca * ct;  rotm[tid][7] =  sa * ct;   // m11
  }

  // --- pre-MLP: 41 -> 64 relu -> 32 relu -> 8 tanh ---
  if (lane < 41) bufB[wid][lane] = x[s * 41 + lane];
  __syncthreads();

  float h1 = b1[lane];
#pragma unroll 4
  for (int k = 0; k < 41; ++k) h1 = fmaf(bufB[wid][k], w1[k * 64 + lane], h1);
  h1 = fmaxf(h1, 0.0f);
  bufA[wid][lane] = h1;
  __syncthreads();

  if (lane < 32) {
    float h2 = b2[lane];
#pragma unroll 4
    for (int k = 0; k < 64; ++k) h2 = fmaf(bufA[wid][k], w2[k * 32 + lane], h2);
    bufB[wid][lane] = fmaxf(h2, 0.0f);
  }
  __syncthreads();

  if (lane < 8) {
    float acc = b3[lane];
#pragma unroll
    for (int k = 0; k < 32; ++k) acc = fmaf(bufB[wid][k], w3[k * 8 + lane], acc);
    float q = tanhf(acc);
    float sh, ch; sincosf(q * PI_HALF, &sh, &ch);
    bufA[wid][lane]     = ch;  // cos(half) per qubit
    bufA[wid][8 + lane] = sh;  // sin(half) per qubit
  }
  __syncthreads();

  // --- init statevector: amp[i] = prod_w (bit_w ? sin_w : cos_w), i = lane+64k
  float c0 = bufA[wid][0], s0 = bufA[wid][8];
  float c1 = bufA[wid][1], s1 = bufA[wid][9];
  float lp = 1.0f;
#pragma unroll
  for (int w = 2; w < 8; ++w) {
    int bit = (lane >> (7 - w)) & 1;
    float cw = bufA[wid][w], sw = bufA[wid][8 + w];
    lp *= bit ? sw : cw;
  }
  float re[4], im[4];
#pragma unroll
  for (int k = 0; k < 4; ++k) {
    float f0 = (k & 2) ? s0 : c0;
    float f1 = (k & 1) ? s1 : c1;
    re[k] = lp * f0 * f1;
    im[k] = 0.0f;
  }

#define RM(L, W) (&rotm[(L) * 8 + (W)][0])
#define ROTS(L)                                                        \
  apply_rot<0>(re, im, RM(L, 0), lane);                                \
  apply_rot<1>(re, im, RM(L, 1), lane);                                \
  apply_rot<2>(re, im, RM(L, 2), lane);                                \
  apply_rot<3>(re, im, RM(L, 3), lane);                                \
  apply_rot<4>(re, im, RM(L, 4), lane);                                \
  apply_rot<5>(re, im, RM(L, 5), lane);                                \
  apply_rot<6>(re, im, RM(L, 6), lane);                                \
  apply_rot<7>(re, im, RM(L, 7), lane);

  // layer 0, r = 1
  ROTS(0)
  apply_cnot<0, 1>(re, im, lane); apply_cnot<1, 2>(re, im, lane);
  apply_cnot<2, 3>(re, im, lane); apply_cnot<3, 4>(re, im, lane);
  apply_cnot<4, 5>(re, im, lane); apply_cnot<5, 6>(re, im, lane);
  apply_cnot<6, 7>(re, im, lane); apply_cnot<7, 0>(re, im, lane);
  // layer 1, r = 2
  ROTS(1)
  apply_cnot<0, 2>(re, im, lane); apply_cnot<1, 3>(re, im, lane);
  apply_cnot<2, 4>(re, im, lane); apply_cnot<3, 5>(re, im, lane);
  apply_cnot<4, 6>(re, im, lane); apply_cnot<5, 7>(re, im, lane);
  apply_cnot<6, 0>(re, im, lane); apply_cnot<7, 1>(re, im, lane);
  // layer 2, r = 3
  ROTS(2)
  apply_cnot<0, 3>(re, im, lane); apply_cnot<1, 4>(re, im, lane);
  apply_cnot<2, 5>(re, im, lane); apply_cnot<3, 6>(re, im, lane);
  apply_cnot<4, 7>(re, im, lane); apply_cnot<5, 0>(re, im, lane);
  apply_cnot<6, 1>(re, im, lane); apply_cnot<7, 2>(re, im, lane);
  // layer 3, r = 4
  ROTS(3)
  apply_cnot<0, 4>(re, im, lane); apply_cnot<1, 5>(re, im, lane);
  apply_cnot<2, 6>(re, im, lane); apply_cnot<3, 7>(re, im, lane);
  apply_cnot<4, 0>(re, im, lane); apply_cnot<5, 1>(re, im, lane);
  apply_cnot<6, 2>(re, im, lane); apply_cnot<7, 3>(re, im, lane);

  // --- expectations <Z_w> = sum_i |amp_i|^2 * (1 - 2*bit_w(i)) ---
  float p0 = re[0] * re[0] + im[0] * im[0];
  float p1 = re[1] * re[1] + im[1] * im[1];
  float p2 = re[2] * re[2] + im[2] * im[2];
  float p3 = re[3] * re[3] + im[3] * im[3];
  float ptot = (p0 + p1) + (p2 + p3);
  float zp[8];
  zp[0] = (p0 + p1) - (p2 + p3);  // wire 0: k bit 1
  zp[1] = (p0 + p2) - (p1 + p3);  // wire 1: k bit 0
#pragma unroll
  for (int w = 2; w < 8; ++w) {
    int bit = (lane >> (7 - w)) & 1;
    zp[w] = bit ? -ptot : ptot;
  }
#pragma unroll
  for (int mm = 1; mm < 64; mm <<= 1) {
#pragma unroll
    for (int w = 0; w < 8; ++w) zp[w] += __shfl_xor(zp[w], mm, 64);
  }
  __syncthreads();
  if (lane < 8) bufA[wid][lane] = zp[lane];
  __syncthreads();

  // --- post-MLP: 8 -> 32 relu -> 16 relu -> 5 ---
  if (lane < 32) {
    float hp = bp1[lane];
#pragma unroll
    for (int k = 0; k < 8; ++k) hp = fmaf(bufA[wid][k], wp1[k * 32 + lane], hp);
    bufB[wid][lane] = fmaxf(hp, 0.0f);
  }
  __syncthreads();
  if (lane < 16) {
    float hp = bp2[lane];
#pragma unroll
    for (int k = 0; k < 32; ++k) hp = fmaf(bufB[wid][k], wp2[k * 16 + lane], hp);
    bufA[wid][lane] = fmaxf(hp, 0.0f);
  }
  __syncthreads();
  if (lane < 5 && s < B) {
    float o = bp3[lane];
#pragma unroll
    for (int k = 0; k < 16; ++k) o = fmaf(bufA[wid][k], wp3[k * 5 + lane], o);
    out[s * 5 + lane] = o;
  }
}

extern "C" void kernel_launch(void* const* d_in, const int* in_sizes, int n_in,
                              void* d_out, int out_size, void* d_ws,
                              size_t ws_size, hipStream_t stream) {
  const float* x   = (const float*)d_in[0];
  const float* w1  = (const float*)d_in[1];
  const float* b1  = (const float*)d_in[2];
  const float* w2  = (const float*)d_in[3];
  const float* b2  = (const float*)d_in[4];
  const float* w3  = (const float*)d_in[5];
  const float* b3  = (const float*)d_in[6];
  const float* qw  = (const float*)d_in[7];
  const float* wp1 = (const float*)d_in[8];
  const float* bp1 = (const float*)d_in[9];
  const float* wp2 = (const float*)d_in[10];
  const float* bp2 = (const float*)d_in[11];
  const float* wp3 = (const float*)d_in[12];
  const float* bp3 = (const float*)d_in[13];
  float* out = (float*)d_out;
  const int B = in_sizes[0] / 41;
  const int blocks = (B + 3) / 4;
  hipLaunchKernelGGL(hqc_kernel, dim3(blocks), dim3(256), 0, stream,
                     x, w1, b1, w2, b2, w3, b3, qw,
                     wp1, bp1, wp2, bp2, wp3, bp3, out, B);
}

// Round 2
// 75.060 us; speedup vs baseline: 1.2891x; 1.2891x over previous
//
#include <hip/hip_runtime.h>
#include <math.h>

#define PI_HALF 1.57079632679489662f

// ---------------------------------------------------------------------------
// Layout: 4 samples / wave, 16 lanes / sample, 16 complex amps / lane.
// Amplitude index i (0..255): bits [7:4] = g (lane&15)  -> qubits 0..3
//                             bits [3:0] = k (reg idx)  -> qubits 4..7
// Qubit w occupies bit (7-w) of i:
//   w in 0..3  -> lane bit (3-w)   (shfl_xor partner)
//   w in 4..7  -> reg-index bit (7-w)  (in-register pair)
// ---------------------------------------------------------------------------

__device__ __forceinline__ void rot_pair(
    float m00r, float m00i, float m01r, float m01i,
    float m10r, float m10i, float m11r, float m11i,
    float& r0, float& i0, float& r1, float& i1) {
  float nr0 = m00r * r0 - m00i * i0 + m01r * r1 - m01i * i1;
  float ni0 = m00r * i0 + m00i * r0 + m01r * i1 + m01i * r1;
  float nr1 = m10r * r0 - m10i * i0 + m11r * r1 - m11i * i1;
  float ni1 = m10r * i0 + m10i * r0 + m11r * i1 + m11i * r1;
  r0 = nr0; i0 = ni0; r1 = nr1; i1 = ni1;
}

template <int W>
__device__ __forceinline__ void apply_rot16(float (&re)[16], float (&im)[16],
                                            const float* m, int g) {
  float4 mA = *(const float4*)(m);      // m00r m00i m01r m01i
  float4 mB = *(const float4*)(m + 4);  // m10r m10i m11r m11i
  if constexpr (W >= 4) {
    constexpr int KM = 1 << (7 - W);  // 8,4,2,1
#pragma unroll
    for (int k = 0; k < 16; ++k) {
      if (!(k & KM)) {
        rot_pair(mA.x, mA.y, mA.z, mA.w, mB.x, mB.y, mB.z, mB.w,
                 re[k], im[k], re[k | KM], im[k | KM]);
      }
    }
  } else {
    constexpr int LM = 1 << (3 - W);  // 8,4,2,1
    const int bit = (g >> (3 - W)) & 1;
    float car = bit ? mB.z : mA.x;
    float cai = bit ? mB.w : mA.y;
    float cbr = bit ? mB.x : mA.z;
    float cbi = bit ? mB.y : mA.w;
#pragma unroll
    for (int k = 0; k < 16; ++k) {
      float pr = __shfl_xor(re[k], LM, 64);
      float pi = __shfl_xor(im[k], LM, 64);
      float orr = re[k], oii = im[k];
      re[k] = car * orr - cai * oii + cbr * pr - cbi * pi;
      im[k] = car * oii + cai * orr + cbr * pi + cbi * pr;
    }
  }
}

// CNOT(C,T): new[i] = bit_C(i) ? old[i ^ mask_T] : old[i]
template <int C, int T>
__device__ __forceinline__ void apply_cnot16(float (&re)[16], float (&im)[16],
                                             int g) {
  if constexpr (C >= 4 && T >= 4) {  // both reg: static register swaps
    constexpr int KC = 1 << (7 - C);
    constexpr int KT = 1 << (7 - T);
#pragma unroll
    for (int k = 0; k < 16; ++k) {
      if ((k & KC) && !(k & KT)) {
        float tr = re[k], ti = im[k];
        re[k] = re[k | KT]; im[k] = im[k | KT];
        re[k | KT] = tr;    im[k | KT] = ti;
      }
    }
  } else if constexpr (C >= 4) {  // C reg, T lane: unconditional shuffle
    constexpr int KC = 1 << (7 - C);
    constexpr int LT = 1 << (3 - T);
#pragma unroll
    for (int k = 0; k < 16; ++k) {
      if (k & KC) {
        re[k] = __shfl_xor(re[k], LT, 64);
        im[k] = __shfl_xor(im[k], LT, 64);
      }
    }
  } else if constexpr (T >= 4) {  // C lane, T reg: per-lane selects
    constexpr int KT = 1 << (7 - T);
    const int cbit = (g >> (3 - C)) & 1;
#pragma unroll
    for (int k = 0; k < 16; ++k) {
      if (!(k & KT)) {
        float r0 = re[k], i0 = im[k], r1 = re[k | KT], i1 = im[k | KT];
        re[k]      = cbit ? r1 : r0;  im[k]      = cbit ? i1 : i0;
        re[k | KT] = cbit ? r0 : r1;  im[k | KT] = cbit ? i0 : i1;
      }
    }
  } else {  // both lane
    constexpr int LT = 1 << (3 - T);
    const int cbit = (g >> (3 - C)) & 1;
#pragma unroll
    for (int k = 0; k < 16; ++k) {
      float pr = __shfl_xor(re[k], LT, 64);
      float pi = __shfl_xor(im[k], LT, 64);
      re[k] = cbit ? pr : re[k];
      im[k] = cbit ? pi : im[k];
    }
  }
}

__device__ __forceinline__ void stage_fence() {
  // Intra-wave LDS producer->consumer: real fence (orders ds ops, waits lgkm)
  __threadfence_block();
}

__global__ __launch_bounds__(256, 4) void hqc_kernel(
    const float* __restrict__ x,
    const float* __restrict__ w1, const float* __restrict__ b1,
    const float* __restrict__ w2, const float* __restrict__ b2,
    const float* __restrict__ w3, const float* __restrict__ b3,
    const float* __restrict__ qw,
    const float* __restrict__ wp1, const float* __restrict__ bp1,
    const float* __restrict__ wp2, const float* __restrict__ bp2,
    const float* __restrict__ wp3, const float* __restrict__ bp3,
    float* __restrict__ out, int B) {
  __shared__ __align__(16) float rotm[32][8];     // l*8+w
  __shared__ float xbuf[16][44];                  // staged x, pad 44
  __shared__ __align__(16) float hbuf[16][68];    // h1 (64), pad 68
  __shared__ float h2buf[16][34];                 // h2 (32), pad 34
  __shared__ float qbuf[16][20];                  // cos[8], sin[8], pad 20
  __shared__ float p1buf[16][34];                 // post1 (32)
  __shared__ float p2buf[16][20];                 // post2 (16)

  const int tid = threadIdx.x;
  const int g = tid & 15;        // lane within 16-lane group
  const int ls = tid >> 4;       // sample slot within block (0..15)
  const int s = blockIdx.x * 16 + ls;
  const bool valid = (s < B);

  // --- Rot matrices (shared by all samples): one thread per gate ---
  if (tid < 32) {
    float phi = qw[tid * 3 + 0];
    float th  = qw[tid * 3 + 1];
    float om  = qw[tid * 3 + 2];
    float st_, ct; sincosf(0.5f * th, &st_, &ct);
    float sa, ca;  sincosf(0.5f * (phi + om), &sa, &ca);
    float sb, cb;  sincosf(0.5f * (phi - om), &sb, &cb);
    rotm[tid][0] =  ca * ct;  rotm[tid][1] = -sa * ct;   // m00
    rotm[tid][2] = -cb * st_; rotm[tid][3] = -sb * st_;  // m01
    rotm[tid][4] =  cb * st_; rotm[tid][5] = -sb * st_;  // m10
    rotm[tid][6] =  ca * ct;  rotm[tid][7] =  sa * ct;   // m11
  }

  // --- stage x (41 floats / sample) ---
  if (valid) {
    xbuf[ls][g]      = x[s * 41 + g];
    xbuf[ls][g + 16] = x[s * 41 + g + 16];
    if (g < 9) xbuf[ls][g + 32] = x[s * 41 + g + 32];
  }
  __syncthreads();  // rotm ready for everyone; xbuf ready (same barrier)

  // --- pre-MLP layer1: 41 -> 64, lane computes 4 cols (float4) ---
  const float4* w1v = (const float4*)w1;  // [41][16]
  float4 a1 = ((const float4*)b1)[g];
#pragma unroll 8
  for (int k = 0; k < 41; ++k) {
    float xk = xbuf[ls][k];
    float4 wv = w1v[k * 16 + g];
    a1.x = fmaf(xk, wv.x, a1.x);
    a1.y = fmaf(xk, wv.y, a1.y);
    a1.z = fmaf(xk, wv.z, a1.z);
    a1.w = fmaf(xk, wv.w, a1.w);
  }
  a1.x = fmaxf(a1.x, 0.f); a1.y = fmaxf(a1.y, 0.f);
  a1.z = fmaxf(a1.z, 0.f); a1.w = fmaxf(a1.w, 0.f);
  *(float4*)(&hbuf[ls][4 * g]) = a1;
  stage_fence();

  // --- layer2: 64 -> 32, lane computes 2 cols (float2) ---
  const float2* w2v = (const float2*)w2;  // [64][16]
  float2 a2 = ((const float2*)b2)[g];
#pragma unroll 8
  for (int k = 0; k < 64; ++k) {
    float hk = hbuf[ls][k];
    float2 wv = w2v[k * 16 + g];
    a2.x = fmaf(hk, wv.x, a2.x);
    a2.y = fmaf(hk, wv.y, a2.y);
  }
  a2.x = fmaxf(a2.x, 0.f); a2.y = fmaxf(a2.y, 0.f);
  h2buf[ls][2 * g]     = a2.x;
  h2buf[ls][2 * g + 1] = a2.y;
  stage_fence();

  // --- layer3: 32 -> 8, tanh, RY encoding ---
  if (g < 8) {
    float acc = b3[g];
#pragma unroll
    for (int k = 0; k < 32; ++k) acc = fmaf(h2buf[ls][k], w3[k * 8 + g], acc);
    float q = tanhf(acc);
    float sh, ch; sincosf(q * PI_HALF, &sh, &ch);
    qbuf[ls][g]     = ch;
    qbuf[ls][8 + g] = sh;
  }
  stage_fence();

  // --- init statevector ---
  float cw[8], sw[8];
#pragma unroll
  for (int w = 0; w < 8; ++w) { cw[w] = qbuf[ls][w]; sw[w] = qbuf[ls][8 + w]; }
  float lp = 1.0f;
#pragma unroll
  for (int w = 0; w < 4; ++w) lp *= ((g >> (3 - w)) & 1) ? sw[w] : cw[w];
  float f45[4], f67[4];
#pragma unroll
  for (int a = 0; a < 4; ++a) {
    f45[a] = ((a & 2) ? sw[4] : cw[4]) * ((a & 1) ? sw[5] : cw[5]);
    f67[a] = ((a & 2) ? sw[6] : cw[6]) * ((a & 1) ? sw[7] : cw[7]);
  }
  float re[16], im[16];
#pragma unroll
  for (int k = 0; k < 16; ++k) {
    re[k] = lp * f45[k >> 2] * f67[k & 3];
    im[k] = 0.0f;
  }

#define RM(L, W) (&rotm[(L) * 8 + (W)][0])
#define ROTS(L)                              \
  apply_rot16<0>(re, im, RM(L, 0), g);       \
  apply_rot16<1>(re, im, RM(L, 1), g);       \
  apply_rot16<2>(re, im, RM(L, 2), g);       \
  apply_rot16<3>(re, im, RM(L, 3), g);       \
  apply_rot16<4>(re, im, RM(L, 4), g);       \
  apply_rot16<5>(re, im, RM(L, 5), g);       \
  apply_rot16<6>(re, im, RM(L, 6), g);       \
  apply_rot16<7>(re, im, RM(L, 7), g);

  // layer 0, r=1
  ROTS(0)
  apply_cnot16<0, 1>(re, im, g); apply_cnot16<1, 2>(re, im, g);
  apply_cnot16<2, 3>(re, im, g); apply_cnot16<3, 4>(re, im, g);
  apply_cnot16<4, 5>(re, im, g); apply_cnot16<5, 6>(re, im, g);
  apply_cnot16<6, 7>(re, im, g); apply_cnot16<7, 0>(re, im, g);
  // layer 1, r=2
  ROTS(1)
  apply_cnot16<0, 2>(re, im, g); apply_cnot16<1, 3>(re, im, g);
  apply_cnot16<2, 4>(re, im, g); apply_cnot16<3, 5>(re, im, g);
  apply_cnot16<4, 6>(re, im, g); apply_cnot16<5, 7>(re, im, g);
  apply_cnot16<6, 0>(re, im, g); apply_cnot16<7, 1>(re, im, g);
  // layer 2, r=3
  ROTS(2)
  apply_cnot16<0, 3>(re, im, g); apply_cnot16<1, 4>(re, im, g);
  apply_cnot16<2, 5>(re, im, g); apply_cnot16<3, 6>(re, im, g);
  apply_cnot16<4, 7>(re, im, g); apply_cnot16<5, 0>(re, im, g);
  apply_cnot16<6, 1>(re, im, g); apply_cnot16<7, 2>(re, im, g);
  // layer 3, r=4
  ROTS(3)
  apply_cnot16<0, 4>(re, im, g); apply_cnot16<1, 5>(re, im, g);
  apply_cnot16<2, 6>(re, im, g); apply_cnot16<3, 7>(re, im, g);
  apply_cnot16<4, 0>(re, im, g); apply_cnot16<5, 1>(re, im, g);
  apply_cnot16<6, 2>(re, im, g); apply_cnot16<7, 3>(re, im, g);

  // --- expectations ---
  float p[16];
#pragma unroll
  for (int k = 0; k < 16; ++k) p[k] = fmaf(re[k], re[k], im[k] * im[k]);
  float tot = 0.f;
#pragma unroll
  for (int k = 0; k < 16; ++k) tot += p[k];
  float s4 = 0.f, s5 = 0.f, s6 = 0.f, s7 = 0.f;
#pragma unroll
  for (int k = 0; k < 16; ++k) {
    if (k & 8) s4 += p[k];
    if (k & 4) s5 += p[k];
    if (k & 2) s6 += p[k];
    if (k & 1) s7 += p[k];
  }
  float zp[8];
  zp[0] = ((g >> 3) & 1) ? -tot : tot;
  zp[1] = ((g >> 2) & 1) ? -tot : tot;
  zp[2] = ((g >> 1) & 1) ? -tot : tot;
  zp[3] = (g & 1) ? -tot : tot;
  zp[4] = fmaf(-2.f, s4, tot);
  zp[5] = fmaf(-2.f, s5, tot);
  zp[6] = fmaf(-2.f, s6, tot);
  zp[7] = fmaf(-2.f, s7, tot);
#pragma unroll
  for (int mm = 1; mm < 16; mm <<= 1) {
#pragma unroll
    for (int w = 0; w < 8; ++w) zp[w] += __shfl_xor(zp[w], mm, 64);
  }

  // --- post-MLP layer1: 8 -> 32, lane computes 2 cols ---
  const float2* wp1v = (const float2*)wp1;  // [8][16]
  float2 q1 = ((const float2*)bp1)[g];
#pragma unroll
  for (int k = 0; k < 8; ++k) {
    float2 wv = wp1v[k * 16 + g];
    q1.x = fmaf(zp[k], wv.x, q1.x);
    q1.y = fmaf(zp[k], wv.y, q1.y);
  }
  q1.x = fmaxf(q1.x, 0.f); q1.y = fmaxf(q1.y, 0.f);
  p1buf[ls][2 * g]     = q1.x;
  p1buf[ls][2 * g + 1] = q1.y;
  stage_fence();

  // --- post layer2: 32 -> 16, lane computes 1 col ---
  float q2 = bp2[g];
#pragma unroll
  for (int k = 0; k < 32; ++k) q2 = fmaf(p1buf[ls][k], wp2[k * 16 + g], q2);
  p2buf[ls][g] = fmaxf(q2, 0.f);
  stage_fence();

  // --- post layer3: 16 -> 5 ---
  if (g < 5 && valid) {
    float o = bp3[g];
#pragma unroll
    for (int k = 0; k < 16; ++k) o = fmaf(p2buf[ls][k], wp3[k * 5 + g], o);
    out[s * 5 + g] = o;
  }
}

extern "C" void kernel_launch(void* const* d_in, const int* in_sizes, int n_in,
                              void* d_out, int out_size, void* d_ws,
                              size_t ws_size, hipStream_t stream) {
  const float* x   = (const float*)d_in[0];
  const float* w1  = (const float*)d_in[1];
  const float* b1  = (const float*)d_in[2];
  const float* w2  = (const float*)d_in[3];
  const float* b2  = (const float*)d_in[4];
  const float* w3  = (const float*)d_in[5];
  const float* b3  = (const float*)d_in[6];
  const float* qw  = (const float*)d_in[7];
  const float* wp1 = (const float*)d_in[8];
  const float* bp1 = (const float*)d_in[9];
  const float* wp2 = (const float*)d_in[10];
  const float* bp2 = (const float*)d_in[11];
  const float* wp3 = (const float*)d_in[12];
  const float* bp3 = (const float*)d_in[13];
  float* out = (float*)d_out;
  const int B = in_sizes[0] / 41;
  const int blocks = (B + 15) / 16;
  hipLaunchKernelGGL(hqc_kernel, dim3(blocks), dim3(256), 0, stream,
                     x, w1, b1, w2, b2, w3, b3, qw,
                     wp1, bp1, wp2, bp2, wp3, bp3, out, B);
}

// Round 3
// 73.995 us; speedup vs baseline: 1.3077x; 1.0144x over previous
//
#include <hip/hip_runtime.h>
#include <math.h>

#define PI_HALF 1.57079632679489662f

// ---------------------------------------------------------------------------
// Layout: 4 samples / wave, 16 lanes / sample, 16 complex amps / lane.
// Amplitude index i (0..255): bits [7:4] = g (lane&15)  -> qubits 0..3
//                             bits [3:0] = k (reg idx)  -> qubits 4..7
// Qubit w occupies bit (7-w) of i:
//   w in 0..3  -> lane bit (3-w)   (shfl_xor partner)
//   w in 4..7  -> reg-index bit (7-w)  (in-register pair)
//
// R3 change vs R2: __launch_bounds__(256) WITHOUT the min-waves hint.
// (256,4) forced VGPR=64 -> ~160B/thread scratch spill (WRITE_SIZE 40MB).
// State must live in registers: let the allocator take ~128-160 VGPRs.
// ---------------------------------------------------------------------------

__device__ __forceinline__ void rot_pair(
    float m00r, float m00i, float m01r, float m01i,
    float m10r, float m10i, float m11r, float m11i,
    float& r0, float& i0, float& r1, float& i1) {
  float nr0 = m00r * r0 - m00i * i0 + m01r * r1 - m01i * i1;
  float ni0 = m00r * i0 + m00i * r0 + m01r * i1 + m01i * r1;
  float nr1 = m10r * r0 - m10i * i0 + m11r * r1 - m11i * i1;
  float ni1 = m10r * i0 + m10i * r0 + m11r * i1 + m11i * r1;
  r0 = nr0; i0 = ni0; r1 = nr1; i1 = ni1;
}

template <int W>
__device__ __forceinline__ void apply_rot16(float (&re)[16], float (&im)[16],
                                            const float* m, int g) {
  float4 mA = *(const float4*)(m);      // m00r m00i m01r m01i
  float4 mB = *(const float4*)(m + 4);  // m10r m10i m11r m11i
  if constexpr (W >= 4) {
    constexpr int KM = 1 << (7 - W);  // 8,4,2,1
#pragma unroll
    for (int k = 0; k < 16; ++k) {
      if (!(k & KM)) {
        rot_pair(mA.x, mA.y, mA.z, mA.w, mB.x, mB.y, mB.z, mB.w,
                 re[k], im[k], re[k | KM], im[k | KM]);
      }
    }
  } else {
    constexpr int LM = 1 << (3 - W);  // 8,4,2,1
    const int bit = (g >> (3 - W)) & 1;
    float car = bit ? mB.z : mA.x;
    float cai = bit ? mB.w : mA.y;
    float cbr = bit ? mB.x : mA.z;
    float cbi = bit ? mB.y : mA.w;
#pragma unroll
    for (int k = 0; k < 16; ++k) {
      float pr = __shfl_xor(re[k], LM, 64);
      float pi = __shfl_xor(im[k], LM, 64);
      float orr = re[k], oii = im[k];
      re[k] = car * orr - cai * oii + cbr * pr - cbi * pi;
      im[k] = car * oii + cai * orr + cbr * pi + cbi * pr;
    }
  }
}

// CNOT(C,T): new[i] = bit_C(i) ? old[i ^ mask_T] : old[i]
template <int C, int T>
__device__ __forceinline__ void apply_cnot16(float (&re)[16], float (&im)[16],
                                             int g) {
  if constexpr (C >= 4 && T >= 4) {  // both reg: static register swaps
    constexpr int KC = 1 << (7 - C);
    constexpr int KT = 1 << (7 - T);
#pragma unroll
    for (int k = 0; k < 16; ++k) {
      if ((k & KC) && !(k & KT)) {
        float tr = re[k], ti = im[k];
        re[k] = re[k | KT]; im[k] = im[k | KT];
        re[k | KT] = tr;    im[k | KT] = ti;
      }
    }
  } else if constexpr (C >= 4) {  // C reg, T lane: unconditional shuffle
    constexpr int KC = 1 << (7 - C);
    constexpr int LT = 1 << (3 - T);
#pragma unroll
    for (int k = 0; k < 16; ++k) {
      if (k & KC) {
        re[k] = __shfl_xor(re[k], LT, 64);
        im[k] = __shfl_xor(im[k], LT, 64);
      }
    }
  } else if constexpr (T >= 4) {  // C lane, T reg: per-lane selects
    constexpr int KT = 1 << (7 - T);
    const int cbit = (g >> (3 - C)) & 1;
#pragma unroll
    for (int k = 0; k < 16; ++k) {
      if (!(k & KT)) {
        float r0 = re[k], i0 = im[k], r1 = re[k | KT], i1 = im[k | KT];
        re[k]      = cbit ? r1 : r0;  im[k]      = cbit ? i1 : i0;
        re[k | KT] = cbit ? r0 : r1;  im[k | KT] = cbit ? i0 : i1;
      }
    }
  } else {  // both lane
    constexpr int LT = 1 << (3 - T);
    const int cbit = (g >> (3 - C)) & 1;
#pragma unroll
    for (int k = 0; k < 16; ++k) {
      float pr = __shfl_xor(re[k], LT, 64);
      float pi = __shfl_xor(im[k], LT, 64);
      re[k] = cbit ? pr : re[k];
      im[k] = cbit ? pi : im[k];
    }
  }
}

__device__ __forceinline__ void stage_fence() {
  // Intra-wave LDS producer->consumer: orders ds ops, waits lgkm
  __threadfence_block();
}

__global__ __launch_bounds__(256) void hqc_kernel(
    const float* __restrict__ x,
    const float* __restrict__ w1, const float* __restrict__ b1,
    const float* __restrict__ w2, const float* __restrict__ b2,
    const float* __restrict__ w3, const float* __restrict__ b3,
    const float* __restrict__ qw,
    const float* __restrict__ wp1, const float* __restrict__ bp1,
    const float* __restrict__ wp2, const float* __restrict__ bp2,
    const float* __restrict__ wp3, const float* __restrict__ bp3,
    float* __restrict__ out, int B) {
  __shared__ __align__(16) float rotm[32][8];     // l*8+w
  __shared__ float xbuf[16][44];                  // staged x, pad 44
  __shared__ __align__(16) float hbuf[16][68];    // h1 (64), pad 68
  __shared__ float h2buf[16][34];                 // h2 (32), pad 34
  __shared__ float qbuf[16][20];                  // cos[8], sin[8], pad 20
  __shared__ float p1buf[16][34];                 // post1 (32)
  __shared__ float p2buf[16][20];                 // post2 (16)

  const int tid = threadIdx.x;
  const int g = tid & 15;        // lane within 16-lane group
  const int ls = tid >> 4;       // sample slot within block (0..15)
  const int s = blockIdx.x * 16 + ls;
  const bool valid = (s < B);

  // --- Rot matrices (shared by all samples): one thread per gate ---
  if (tid < 32) {
    float phi = qw[tid * 3 + 0];
    float th  = qw[tid * 3 + 1];
    float om  = qw[tid * 3 + 2];
    float st_, ct; sincosf(0.5f * th, &st_, &ct);
    float sa, ca;  sincosf(0.5f * (phi + om), &sa, &ca);
    float sb, cb;  sincosf(0.5f * (phi - om), &sb, &cb);
    rotm[tid][0] =  ca * ct;  rotm[tid][1] = -sa * ct;   // m00
    rotm[tid][2] = -cb * st_; rotm[tid][3] = -sb * st_;  // m01
    rotm[tid][4] =  cb * st_; rotm[tid][5] = -sb * st_;  // m10
    rotm[tid][6] =  ca * ct;  rotm[tid][7] =  sa * ct;   // m11
  }

  // --- stage x (41 floats / sample) ---
  if (valid) {
    xbuf[ls][g]      = x[s * 41 + g];
    xbuf[ls][g + 16] = x[s * 41 + g + 16];
    if (g < 9) xbuf[ls][g + 32] = x[s * 41 + g + 32];
  }
  __syncthreads();  // rotm ready for everyone; xbuf ready (same barrier)

  // --- pre-MLP layer1: 41 -> 64, lane computes 4 cols (float4) ---
  const float4* w1v = (const float4*)w1;  // [41][16]
  float4 a1 = ((const float4*)b1)[g];
#pragma unroll 8
  for (int k = 0; k < 41; ++k) {
    float xk = xbuf[ls][k];
    float4 wv = w1v[k * 16 + g];
    a1.x = fmaf(xk, wv.x, a1.x);
    a1.y = fmaf(xk, wv.y, a1.y);
    a1.z = fmaf(xk, wv.z, a1.z);
    a1.w = fmaf(xk, wv.w, a1.w);
  }
  a1.x = fmaxf(a1.x, 0.f); a1.y = fmaxf(a1.y, 0.f);
  a1.z = fmaxf(a1.z, 0.f); a1.w = fmaxf(a1.w, 0.f);
  *(float4*)(&hbuf[ls][4 * g]) = a1;
  stage_fence();

  // --- layer2: 64 -> 32, lane computes 2 cols (float2) ---
  const float2* w2v = (const float2*)w2;  // [64][16]
  float2 a2 = ((const float2*)b2)[g];
#pragma unroll 8
  for (int k = 0; k < 64; ++k) {
    float hk = hbuf[ls][k];
    float2 wv = w2v[k * 16 + g];
    a2.x = fmaf(hk, wv.x, a2.x);
    a2.y = fmaf(hk, wv.y, a2.y);
  }
  a2.x = fmaxf(a2.x, 0.f); a2.y = fmaxf(a2.y, 0.f);
  h2buf[ls][2 * g]     = a2.x;
  h2buf[ls][2 * g + 1] = a2.y;
  stage_fence();

  // --- layer3: 32 -> 8, tanh, RY encoding ---
  if (g < 8) {
    float acc = b3[g];
#pragma unroll
    for (int k = 0; k < 32; ++k) acc = fmaf(h2buf[ls][k], w3[k * 8 + g], acc);
    float q = tanhf(acc);
    float sh, ch; sincosf(q * PI_HALF, &sh, &ch);
    qbuf[ls][g]     = ch;
    qbuf[ls][8 + g] = sh;
  }
  stage_fence();

  // --- init statevector ---
  float cw[8], sw[8];
#pragma unroll
  for (int w = 0; w < 8; ++w) { cw[w] = qbuf[ls][w]; sw[w] = qbuf[ls][8 + w]; }
  float lp = 1.0f;
#pragma unroll
  for (int w = 0; w < 4; ++w) lp *= ((g >> (3 - w)) & 1) ? sw[w] : cw[w];
  float f45[4], f67[4];
#pragma unroll
  for (int a = 0; a < 4; ++a) {
    f45[a] = ((a & 2) ? sw[4] : cw[4]) * ((a & 1) ? sw[5] : cw[5]);
    f67[a] = ((a & 2) ? sw[6] : cw[6]) * ((a & 1) ? sw[7] : cw[7]);
  }
  float re[16], im[16];
#pragma unroll
  for (int k = 0; k < 16; ++k) {
    re[k] = lp * f45[k >> 2] * f67[k & 3];
    im[k] = 0.0f;
  }

#define RM(L, W) (&rotm[(L) * 8 + (W)][0])
#define ROTS(L)                              \
  apply_rot16<0>(re, im, RM(L, 0), g);       \
  apply_rot16<1>(re, im, RM(L, 1), g);       \
  apply_rot16<2>(re, im, RM(L, 2), g);       \
  apply_rot16<3>(re, im, RM(L, 3), g);       \
  apply_rot16<4>(re, im, RM(L, 4), g);       \
  apply_rot16<5>(re, im, RM(L, 5), g);       \
  apply_rot16<6>(re, im, RM(L, 6), g);       \
  apply_rot16<7>(re, im, RM(L, 7), g);

  // layer 0, r=1
  ROTS(0)
  apply_cnot16<0, 1>(re, im, g); apply_cnot16<1, 2>(re, im, g);
  apply_cnot16<2, 3>(re, im, g); apply_cnot16<3, 4>(re, im, g);
  apply_cnot16<4, 5>(re, im, g); apply_cnot16<5, 6>(re, im, g);
  apply_cnot16<6, 7>(re, im, g); apply_cnot16<7, 0>(re, im, g);
  // layer 1, r=2
  ROTS(1)
  apply_cnot16<0, 2>(re, im, g); apply_cnot16<1, 3>(re, im, g);
  apply_cnot16<2, 4>(re, im, g); apply_cnot16<3, 5>(re, im, g);
  apply_cnot16<4, 6>(re, im, g); apply_cnot16<5, 7>(re, im, g);
  apply_cnot16<6, 0>(re, im, g); apply_cnot16<7, 1>(re, im, g);
  // layer 2, r=3
  ROTS(2)
  apply_cnot16<0, 3>(re, im, g); apply_cnot16<1, 4>(re, im, g);
  apply_cnot16<2, 5>(re, im, g); apply_cnot16<3, 6>(re, im, g);
  apply_cnot16<4, 7>(re, im, g); apply_cnot16<5, 0>(re, im, g);
  apply_cnot16<6, 1>(re, im, g); apply_cnot16<7, 2>(re, im, g);
  // layer 3, r=4
  ROTS(3)
  apply_cnot16<0, 4>(re, im, g); apply_cnot16<1, 5>(re, im, g);
  apply_cnot16<2, 6>(re, im, g); apply_cnot16<3, 7>(re, im, g);
  apply_cnot16<4, 0>(re, im, g); apply_cnot16<5, 1>(re, im, g);
  apply_cnot16<6, 2>(re, im, g); apply_cnot16<7, 3>(re, im, g);

  // --- expectations ---
  float p[16];
#pragma unroll
  for (int k = 0; k < 16; ++k) p[k] = fmaf(re[k], re[k], im[k] * im[k]);
  float tot = 0.f;
#pragma unroll
  for (int k = 0; k < 16; ++k) tot += p[k];
  float s4 = 0.f, s5 = 0.f, s6 = 0.f, s7 = 0.f;
#pragma unroll
  for (int k = 0; k < 16; ++k) {
    if (k & 8) s4 += p[k];
    if (k & 4) s5 += p[k];
    if (k & 2) s6 += p[k];
    if (k & 1) s7 += p[k];
  }
  float zp[8];
  zp[0] = ((g >> 3) & 1) ? -tot : tot;
  zp[1] = ((g >> 2) & 1) ? -tot : tot;
  zp[2] = ((g >> 1) & 1) ? -tot : tot;
  zp[3] = (g & 1) ? -tot : tot;
  zp[4] = fmaf(-2.f, s4, tot);
  zp[5] = fmaf(-2.f, s5, tot);
  zp[6] = fmaf(-2.f, s6, tot);
  zp[7] = fmaf(-2.f, s7, tot);
#pragma unroll
  for (int mm = 1; mm < 16; mm <<= 1) {
#pragma unroll
    for (int w = 0; w < 8; ++w) zp[w] += __shfl_xor(zp[w], mm, 64);
  }

  // --- post-MLP layer1: 8 -> 32, lane computes 2 cols ---
  const float2* wp1v = (const float2*)wp1;  // [8][16]
  float2 q1 = ((const float2*)bp1)[g];
#pragma unroll
  for (int k = 0; k < 8; ++k) {
    float2 wv = wp1v[k * 16 + g];
    q1.x = fmaf(zp[k], wv.x, q1.x);
    q1.y = fmaf(zp[k], wv.y, q1.y);
  }
  q1.x = fmaxf(q1.x, 0.f); q1.y = fmaxf(q1.y, 0.f);
  p1buf[ls][2 * g]     = q1.x;
  p1buf[ls][2 * g + 1] = q1.y;
  stage_fence();

  // --- post layer2: 32 -> 16, lane computes 1 col ---
  float q2 = bp2[g];
#pragma unroll
  for (int k = 0; k < 32; ++k) q2 = fmaf(p1buf[ls][k], wp2[k * 16 + g], q2);
  p2buf[ls][g] = fmaxf(q2, 0.f);
  stage_fence();

  // --- post layer3: 16 -> 5 ---
  if (g < 5 && valid) {
    float o = bp3[g];
#pragma unroll
    for (int k = 0; k < 16; ++k) o = fmaf(p2buf[ls][k], wp3[k * 5 + g], o);
    out[s * 5 + g] = o;
  }
}

extern "C" void kernel_launch(void* const* d_in, const int* in_sizes, int n_in,
                              void* d_out, int out_size, void* d_ws,
                              size_t ws_size, hipStream_t stream) {
  const float* x   = (const float*)d_in[0];
  const float* w1  = (const float*)d_in[1];
  const float* b1  = (const float*)d_in[2];
  const float* w2  = (const float*)d_in[3];
  const float* b2  = (const float*)d_in[4];
  const float* w3  = (const float*)d_in[5];
  const float* b3  = (const float*)d_in[6];
  const float* qw  = (const float*)d_in[7];
  const float* wp1 = (const float*)d_in[8];
  const float* bp1 = (const float*)d_in[9];
  const float* wp2 = (const float*)d_in[10];
  const float* bp2 = (const float*)d_in[11];
  const float* wp3 = (const float*)d_in[12];
  const float* bp3 = (const float*)d_in[13];
  float* out = (float*)d_out;
  const int B = in_sizes[0] / 41;
  const int blocks = (B + 15) / 16;
  hipLaunchKernelGGL(hqc_kernel, dim3(blocks), dim3(256), 0, stream,
                     x, w1, b1, w2, b2, w3, b3, qw,
                     wp1, bp1, wp2, bp2, wp3, bp3, out, B);
}

// Round 4
// 62.072 us; speedup vs baseline: 1.5588x; 1.1921x over previous
//
#include <hip/hip_runtime.h>
#include <math.h>

#define PI_HALF 1.57079632679489662f

// ---------------------------------------------------------------------------
// Layout: 4 samples / wave, 16 lanes / sample, 16 complex amps / lane.
// Amplitude index i (0..255): bits [7:4] = g (lane&15)  -> qubits 0..3
//                             bits [3:0] = k (reg idx)  -> qubits 4..7
// Qubit w occupies bit (7-w) of i:
//   w in 0..3  -> lane bit (3-w)   (DPP lane exchange)
//   w in 4..7  -> reg-index bit (7-w)  (in-register pair)
//
// R4 change vs R3: all __shfl_xor -> DPP (VALU lane permutes). ds_swizzle
// loads the per-CU-shared DS pipe (~900 ops/wave ~= 50-60us/CU); DPP runs
// on the VALU with ~2cyc latency and no lgkm wait.
//   xor1 = quad_perm 0xB1, xor2 = quad_perm 0x4E, xor8 = row_ror:8 0x128,
//   xor4 = row_half_mirror 0x141 (xor7) o quad_perm 0x1B (xor3).
// ---------------------------------------------------------------------------

template <int CTRL>
__device__ __forceinline__ float dpp_mov(float v) {
  int r = __builtin_amdgcn_update_dpp(0, __float_as_int(v), CTRL, 0xf, 0xf, true);
  return __int_as_float(r);
}

template <int MASK>  // MASK in {1,2,4,8}, xor within 16-lane rows
__device__ __forceinline__ float lane_xor(float v) {
  if constexpr (MASK == 1) {
    return dpp_mov<0xB1>(v);              // quad_perm [1,0,3,2]
  } else if constexpr (MASK == 2) {
    return dpp_mov<0x4E>(v);              // quad_perm [2,3,0,1]
  } else if constexpr (MASK == 8) {
    return dpp_mov<0x128>(v);             // row_ror:8
  } else {                                // MASK == 4: xor7 then xor3
    return dpp_mov<0x1B>(dpp_mov<0x141>(v));
  }
}

__device__ __forceinline__ void rot_pair(
    float m00r, float m00i, float m01r, float m01i,
    float m10r, float m10i, float m11r, float m11i,
    float& r0, float& i0, float& r1, float& i1) {
  float nr0 = m00r * r0 - m00i * i0 + m01r * r1 - m01i * i1;
  float ni0 = m00r * i0 + m00i * r0 + m01r * i1 + m01i * r1;
  float nr1 = m10r * r0 - m10i * i0 + m11r * r1 - m11i * i1;
  float ni1 = m10r * i0 + m10i * r0 + m11r * i1 + m11i * r1;
  r0 = nr0; i0 = ni0; r1 = nr1; i1 = ni1;
}

template <int W>
__device__ __forceinline__ void apply_rot16(float (&re)[16], float (&im)[16],
                                            const float* m, int g) {
  float4 mA = *(const float4*)(m);      // m00r m00i m01r m01i
  float4 mB = *(const float4*)(m + 4);  // m10r m10i m11r m11i
  if constexpr (W >= 4) {
    constexpr int KM = 1 << (7 - W);  // 8,4,2,1
#pragma unroll
    for (int k = 0; k < 16; ++k) {
      if (!(k & KM)) {
        rot_pair(mA.x, mA.y, mA.z, mA.w, mB.x, mB.y, mB.z, mB.w,
                 re[k], im[k], re[k | KM], im[k | KM]);
      }
    }
  } else {
    constexpr int LM = 1 << (3 - W);  // 8,4,2,1
    const int bit = (g >> (3 - W)) & 1;
    float car = bit ? mB.z : mA.x;
    float cai = bit ? mB.w : mA.y;
    float cbr = bit ? mB.x : mA.z;
    float cbi = bit ? mB.y : mA.w;
#pragma unroll
    for (int k = 0; k < 16; ++k) {
      float pr = lane_xor<LM>(re[k]);
      float pi = lane_xor<LM>(im[k]);
      float orr = re[k], oii = im[k];
      re[k] = car * orr - cai * oii + cbr * pr - cbi * pi;
      im[k] = car * oii + cai * orr + cbr * pi + cbi * pr;
    }
  }
}

// CNOT(C,T): new[i] = bit_C(i) ? old[i ^ mask_T] : old[i]
template <int C, int T>
__device__ __forceinline__ void apply_cnot16(float (&re)[16], float (&im)[16],
                                             int g) {
  if constexpr (C >= 4 && T >= 4) {  // both reg: static register swaps
    constexpr int KC = 1 << (7 - C);
    constexpr int KT = 1 << (7 - T);
#pragma unroll
    for (int k = 0; k < 16; ++k) {
      if ((k & KC) && !(k & KT)) {
        float tr = re[k], ti = im[k];
        re[k] = re[k | KT]; im[k] = im[k | KT];
        re[k | KT] = tr;    im[k | KT] = ti;
      }
    }
  } else if constexpr (C >= 4) {  // C reg, T lane: unconditional exchange
    constexpr int KC = 1 << (7 - C);
    constexpr int LT = 1 << (3 - T);
#pragma unroll
    for (int k = 0; k < 16; ++k) {
      if (k & KC) {
        re[k] = lane_xor<LT>(re[k]);
        im[k] = lane_xor<LT>(im[k]);
      }
    }
  } else if constexpr (T >= 4) {  // C lane, T reg: per-lane selects
    constexpr int KT = 1 << (7 - T);
    const int cbit = (g >> (3 - C)) & 1;
#pragma unroll
    for (int k = 0; k < 16; ++k) {
      if (!(k & KT)) {
        float r0 = re[k], i0 = im[k], r1 = re[k | KT], i1 = im[k | KT];
        re[k]      = cbit ? r1 : r0;  im[k]      = cbit ? i1 : i0;
        re[k | KT] = cbit ? r0 : r1;  im[k | KT] = cbit ? i0 : i1;
      }
    }
  } else {  // both lane
    constexpr int LT = 1 << (3 - T);
    const int cbit = (g >> (3 - C)) & 1;
#pragma unroll
    for (int k = 0; k < 16; ++k) {
      float pr = lane_xor<LT>(re[k]);
      float pi = lane_xor<LT>(im[k]);
      re[k] = cbit ? pr : re[k];
      im[k] = cbit ? pi : im[k];
    }
  }
}

__device__ __forceinline__ void stage_fence() {
  // Intra-wave LDS producer->consumer: orders ds ops, waits lgkm
  __threadfence_block();
}

__global__ __launch_bounds__(256) void hqc_kernel(
    const float* __restrict__ x,
    const float* __restrict__ w1, const float* __restrict__ b1,
    const float* __restrict__ w2, const float* __restrict__ b2,
    const float* __restrict__ w3, const float* __restrict__ b3,
    const float* __restrict__ qw,
    const float* __restrict__ wp1, const float* __restrict__ bp1,
    const float* __restrict__ wp2, const float* __restrict__ bp2,
    const float* __restrict__ wp3, const float* __restrict__ bp3,
    float* __restrict__ out, int B) {
  __shared__ __align__(16) float rotm[32][8];     // l*8+w
  __shared__ float xbuf[16][44];                  // staged x, pad 44
  __shared__ __align__(16) float hbuf[16][68];    // h1 (64), pad 68
  __shared__ float h2buf[16][34];                 // h2 (32), pad 34
  __shared__ float qbuf[16][20];                  // cos[8], sin[8], pad 20
  __shared__ float p1buf[16][34];                 // post1 (32)
  __shared__ float p2buf[16][20];                 // post2 (16)

  const int tid = threadIdx.x;
  const int g = tid & 15;        // lane within 16-lane group
  const int ls = tid >> 4;       // sample slot within block (0..15)
  const int s = blockIdx.x * 16 + ls;
  const bool valid = (s < B);

  // --- Rot matrices (shared by all samples): one thread per gate ---
  if (tid < 32) {
    float phi = qw[tid * 3 + 0];
    float th  = qw[tid * 3 + 1];
    float om  = qw[tid * 3 + 2];
    float st_, ct; sincosf(0.5f * th, &st_, &ct);
    float sa, ca;  sincosf(0.5f * (phi + om), &sa, &ca);
    float sb, cb;  sincosf(0.5f * (phi - om), &sb, &cb);
    rotm[tid][0] =  ca * ct;  rotm[tid][1] = -sa * ct;   // m00
    rotm[tid][2] = -cb * st_; rotm[tid][3] = -sb * st_;  // m01
    rotm[tid][4] =  cb * st_; rotm[tid][5] = -sb * st_;  // m10
    rotm[tid][6] =  ca * ct;  rotm[tid][7] =  sa * ct;   // m11
  }

  // --- stage x (41 floats / sample) ---
  if (valid) {
    xbuf[ls][g]      = x[s * 41 + g];
    xbuf[ls][g + 16] = x[s * 41 + g + 16];
    if (g < 9) xbuf[ls][g + 32] = x[s * 41 + g + 32];
  }
  __syncthreads();  // rotm ready for everyone; xbuf ready (same barrier)

  // --- pre-MLP layer1: 41 -> 64, lane computes 4 cols (float4) ---
  const float4* w1v = (const float4*)w1;  // [41][16]
  float4 a1 = ((const float4*)b1)[g];
#pragma unroll 8
  for (int k = 0; k < 41; ++k) {
    float xk = xbuf[ls][k];
    float4 wv = w1v[k * 16 + g];
    a1.x = fmaf(xk, wv.x, a1.x);
    a1.y = fmaf(xk, wv.y, a1.y);
    a1.z = fmaf(xk, wv.z, a1.z);
    a1.w = fmaf(xk, wv.w, a1.w);
  }
  a1.x = fmaxf(a1.x, 0.f); a1.y = fmaxf(a1.y, 0.f);
  a1.z = fmaxf(a1.z, 0.f); a1.w = fmaxf(a1.w, 0.f);
  *(float4*)(&hbuf[ls][4 * g]) = a1;
  stage_fence();

  // --- layer2: 64 -> 32, lane computes 2 cols (float2) ---
  const float2* w2v = (const float2*)w2;  // [64][16]
  float2 a2 = ((const float2*)b2)[g];
#pragma unroll 8
  for (int k = 0; k < 64; ++k) {
    float hk = hbuf[ls][k];
    float2 wv = w2v[k * 16 + g];
    a2.x = fmaf(hk, wv.x, a2.x);
    a2.y = fmaf(hk, wv.y, a2.y);
  }
  a2.x = fmaxf(a2.x, 0.f); a2.y = fmaxf(a2.y, 0.f);
  h2buf[ls][2 * g]     = a2.x;
  h2buf[ls][2 * g + 1] = a2.y;
  stage_fence();

  // --- layer3: 32 -> 8, tanh, RY encoding ---
  if (g < 8) {
    float acc = b3[g];
#pragma unroll
    for (int k = 0; k < 32; ++k) acc = fmaf(h2buf[ls][k], w3[k * 8 + g], acc);
    float q = tanhf(acc);
    float sh, ch; sincosf(q * PI_HALF, &sh, &ch);
    qbuf[ls][g]     = ch;
    qbuf[ls][8 + g] = sh;
  }
  stage_fence();

  // --- init statevector ---
  float cw[8], sw[8];
#pragma unroll
  for (int w = 0; w < 8; ++w) { cw[w] = qbuf[ls][w]; sw[w] = qbuf[ls][8 + w]; }
  float lp = 1.0f;
#pragma unroll
  for (int w = 0; w < 4; ++w) lp *= ((g >> (3 - w)) & 1) ? sw[w] : cw[w];
  float f45[4], f67[4];
#pragma unroll
  for (int a = 0; a < 4; ++a) {
    f45[a] = ((a & 2) ? sw[4] : cw[4]) * ((a & 1) ? sw[5] : cw[5]);
    f67[a] = ((a & 2) ? sw[6] : cw[6]) * ((a & 1) ? sw[7] : cw[7]);
  }
  float re[16], im[16];
#pragma unroll
  for (int k = 0; k < 16; ++k) {
    re[k] = lp * f45[k >> 2] * f67[k & 3];
    im[k] = 0.0f;
  }

#define RM(L, W) (&rotm[(L) * 8 + (W)][0])
#define ROTS(L)                              \
  apply_rot16<0>(re, im, RM(L, 0), g);       \
  apply_rot16<1>(re, im, RM(L, 1), g);       \
  apply_rot16<2>(re, im, RM(L, 2), g);       \
  apply_rot16<3>(re, im, RM(L, 3), g);       \
  apply_rot16<4>(re, im, RM(L, 4), g);       \
  apply_rot16<5>(re, im, RM(L, 5), g);       \
  apply_rot16<6>(re, im, RM(L, 6), g);       \
  apply_rot16<7>(re, im, RM(L, 7), g);

  // layer 0, r=1
  ROTS(0)
  apply_cnot16<0, 1>(re, im, g); apply_cnot16<1, 2>(re, im, g);
  apply_cnot16<2, 3>(re, im, g); apply_cnot16<3, 4>(re, im, g);
  apply_cnot16<4, 5>(re, im, g); apply_cnot16<5, 6>(re, im, g);
  apply_cnot16<6, 7>(re, im, g); apply_cnot16<7, 0>(re, im, g);
  // layer 1, r=2
  ROTS(1)
  apply_cnot16<0, 2>(re, im, g); apply_cnot16<1, 3>(re, im, g);
  apply_cnot16<2, 4>(re, im, g); apply_cnot16<3, 5>(re, im, g);
  apply_cnot16<4, 6>(re, im, g); apply_cnot16<5, 7>(re, im, g);
  apply_cnot16<6, 0>(re, im, g); apply_cnot16<7, 1>(re, im, g);
  // layer 2, r=3
  ROTS(2)
  apply_cnot16<0, 3>(re, im, g); apply_cnot16<1, 4>(re, im, g);
  apply_cnot16<2, 5>(re, im, g); apply_cnot16<3, 6>(re, im, g);
  apply_cnot16<4, 7>(re, im, g); apply_cnot16<5, 0>(re, im, g);
  apply_cnot16<6, 1>(re, im, g); apply_cnot16<7, 2>(re, im, g);
  // layer 3, r=4
  ROTS(3)
  apply_cnot16<0, 4>(re, im, g); apply_cnot16<1, 5>(re, im, g);
  apply_cnot16<2, 6>(re, im, g); apply_cnot16<3, 7>(re, im, g);
  apply_cnot16<4, 0>(re, im, g); apply_cnot16<5, 1>(re, im, g);
  apply_cnot16<6, 2>(re, im, g); apply_cnot16<7, 3>(re, im, g);

  // --- expectations ---
  float p[16];
#pragma unroll
  for (int k = 0; k < 16; ++k) p[k] = fmaf(re[k], re[k], im[k] * im[k]);
  float tot = 0.f;
#pragma unroll
  for (int k = 0; k < 16; ++k) tot += p[k];
  float s4 = 0.f, s5 = 0.f, s6 = 0.f, s7 = 0.f;
#pragma unroll
  for (int k = 0; k < 16; ++k) {
    if (k & 8) s4 += p[k];
    if (k & 4) s5 += p[k];
    if (k & 2) s6 += p[k];
    if (k & 1) s7 += p[k];
  }
  float zp[8];
  zp[0] = ((g >> 3) & 1) ? -tot : tot;
  zp[1] = ((g >> 2) & 1) ? -tot : tot;
  zp[2] = ((g >> 1) & 1) ? -tot : tot;
  zp[3] = (g & 1) ? -tot : tot;
  zp[4] = fmaf(-2.f, s4, tot);
  zp[5] = fmaf(-2.f, s5, tot);
  zp[6] = fmaf(-2.f, s6, tot);
  zp[7] = fmaf(-2.f, s7, tot);
#pragma unroll
  for (int w = 0; w < 8; ++w) zp[w] += lane_xor<1>(zp[w]);
#pragma unroll
  for (int w = 0; w < 8; ++w) zp[w] += lane_xor<2>(zp[w]);
#pragma unroll
  for (int w = 0; w < 8; ++w) zp[w] += lane_xor<4>(zp[w]);
#pragma unroll
  for (int w = 0; w < 8; ++w) zp[w] += lane_xor<8>(zp[w]);

  // --- post-MLP layer1: 8 -> 32, lane computes 2 cols ---
  const float2* wp1v = (const float2*)wp1;  // [8][16]
  float2 q1 = ((const float2*)bp1)[g];
#pragma unroll
  for (int k = 0; k < 8; ++k) {
    float2 wv = wp1v[k * 16 + g];
    q1.x = fmaf(zp[k], wv.x, q1.x);
    q1.y = fmaf(zp[k], wv.y, q1.y);
  }
  q1.x = fmaxf(q1.x, 0.f); q1.y = fmaxf(q1.y, 0.f);
  p1buf[ls][2 * g]     = q1.x;
  p1buf[ls][2 * g + 1] = q1.y;
  stage_fence();

  // --- post layer2: 32 -> 16, lane computes 1 col ---
  float q2 = bp2[g];
#pragma unroll
  for (int k = 0; k < 32; ++k) q2 = fmaf(p1buf[ls][k], wp2[k * 16 + g], q2);
  p2buf[ls][g] = fmaxf(q2, 0.f);
  stage_fence();

  // --- post layer3: 16 -> 5 ---
  if (g < 5 && valid) {
    float o = bp3[g];
#pragma unroll
    for (int k = 0; k < 16; ++k) o = fmaf(p2buf[ls][k], wp3[k * 5 + g], o);
    out[s * 5 + g] = o;
  }
}

extern "C" void kernel_launch(void* const* d_in, const int* in_sizes, int n_in,
                              void* d_out, int out_size, void* d_ws,
                              size_t ws_size, hipStream_t stream) {
  const float* x   = (const float*)d_in[0];
  const float* w1  = (const float*)d_in[1];
  const float* b1  = (const float*)d_in[2];
  const float* w2  = (const float*)d_in[3];
  const float* b2  = (const float*)d_in[4];
  const float* w3  = (const float*)d_in[5];
  const float* b3  = (const float*)d_in[6];
  const float* qw  = (const float*)d_in[7];
  const float* wp1 = (const float*)d_in[8];
  const float* bp1 = (const float*)d_in[9];
  const float* wp2 = (const float*)d_in[10];
  const float* bp2 = (const float*)d_in[11];
  const float* wp3 = (const float*)d_in[12];
  const float* bp3 = (const float*)d_in[13];
  float* out = (float*)d_out;
  const int B = in_sizes[0] / 41;
  const int blocks = (B + 15) / 16;
  hipLaunchKernelGGL(hqc_kernel, dim3(blocks), dim3(256), 0, stream,
                     x, w1, b1, w2, b2, w3, b3, qw,
                     wp1, bp1, wp2, bp2, wp3, bp3, out, B);
}

// Round 5
// 42.580 us; speedup vs baseline: 2.2724x; 1.4578x over previous
//
#include <hip/hip_runtime.h>
#include <math.h>

#define PI_HALF 1.57079632679489662f

typedef float v2f __attribute__((ext_vector_type(2)));

// ---------------------------------------------------------------------------
// Layout: 4 samples / wave, 16 lanes / sample.
// Amplitude index i (0..255): bits [7:4] = g (lane&15) -> qubits 0..3
//                             bits [3:0] = k           -> qubits 4..7
// k = 2*j + h: state held as v2f RE[8], IM[8]; RE[j] = (re[2j], re[2j+1]).
//   qubit 4 -> j bit2, qubit 5 -> j bit1, qubit 6 -> j bit0, qubit 7 -> h.
// R5 change vs R4: packed fp32 (v_pk_fma_f32) for all gate math except q7,
// conj-structure (m11=conj(m00), m10=-conj(m01)) so each gate needs only 4
// coefficients, packed MLP accumulators.
// ---------------------------------------------------------------------------

__device__ __forceinline__ v2f sp(float x) { v2f r; r.x = x; r.y = x; return r; }
__device__ __forceinline__ v2f pkfma(v2f a, v2f b, v2f c) {
  return __builtin_elementwise_fma(a, b, c);
}

template <int CTRL>
__device__ __forceinline__ float dpp_mov(float v) {
  int r = __builtin_amdgcn_update_dpp(0, __float_as_int(v), CTRL, 0xf, 0xf, true);
  return __int_as_float(r);
}
template <int MASK>  // xor within 16-lane rows, MASK in {1,2,4,8}
__device__ __forceinline__ float lane_xor(float v) {
  if constexpr (MASK == 1) return dpp_mov<0xB1>(v);        // quad_perm [1,0,3,2]
  else if constexpr (MASK == 2) return dpp_mov<0x4E>(v);   // quad_perm [2,3,0,1]
  else if constexpr (MASK == 8) return dpp_mov<0x128>(v);  // row_ror:8
  else return dpp_mov<0x1B>(dpp_mov<0x141>(v));            // xor7 o xor3
}
template <int MASK>
__device__ __forceinline__ v2f dpp2(v2f v) {
  v2f r; r.x = lane_xor<MASK>(v.x); r.y = lane_xor<MASK>(v.y); return r;
}

// --- Rot gates.  mA = (m00r, m00i, m01r, m01i);  m11=conj(m00), m10=-conj(m01)
template <int W>  // lane qubit, W in 0..3
__device__ __forceinline__ void rot_lane(v2f (&RE)[8], v2f (&IM)[8],
                                         const float4 mA, int g) {
  constexpr int LM = 1 << (3 - W);
  const unsigned bit = (g >> (3 - W)) & 1u;
  const int sgn = (int)(bit << 31);
  v2f Av = sp(mA.x);
  v2f Bv = sp(__int_as_float(__float_as_int(mA.y) ^ sgn));
  v2f Cv = sp(__int_as_float(__float_as_int(mA.z) ^ sgn));
  v2f Dv = sp(mA.w);
#pragma unroll
  for (int j = 0; j < 8; ++j) {
    v2f pr = dpp2<LM>(RE[j]);
    v2f pi = dpp2<LM>(IM[j]);
    v2f nr = pkfma(-Dv, pi, pkfma(Cv, pr, pkfma(-Bv, IM[j], Av * RE[j])));
    v2f ni = pkfma( Dv, pr, pkfma(Cv, pi, pkfma( Bv, RE[j], Av * IM[j])));
    RE[j] = nr; IM[j] = ni;
  }
}

template <int JM>  // reg qubit via j-bit: q4 JM=4, q5 JM=2, q6 JM=1
__device__ __forceinline__ void rot_regj(v2f (&RE)[8], v2f (&IM)[8],
                                         const float4 mA) {
  v2f M0r = sp(mA.x), M0i = sp(mA.y), M1r = sp(mA.z), M1i = sp(mA.w);
#pragma unroll
  for (int j = 0; j < 8; ++j) {
    if (!(j & JM)) {
      const int j1 = j | JM;
      v2f r0 = RE[j], i0 = IM[j], r1 = RE[j1], i1 = IM[j1];
      RE[j]  = pkfma(-M1i, i1, pkfma(M1r, r1, pkfma(-M0i, i0, M0r * r0)));
      IM[j]  = pkfma( M1i, r1, pkfma(M1r, i1, pkfma( M0i, r0, M0r * i0)));
      RE[j1] = pkfma( M0i, i1, pkfma(M0r, r1, pkfma(-M1i, i0, (-M1r) * r0)));
      IM[j1] = pkfma(-M0i, r1, pkfma(M0r, i1, pkfma( M1i, r0, (-M1r) * i0)));
    }
  }
}

__device__ __forceinline__ void rot_regh(v2f (&RE)[8], v2f (&IM)[8],
                                         const float4 mA) {  // q7 (h bit)
#pragma unroll
  for (int j = 0; j < 8; ++j) {
    float r0 = RE[j].x, i0 = IM[j].x, r1 = RE[j].y, i1 = IM[j].y;
    RE[j].x = fmaf(-mA.w, i1, fmaf(mA.z, r1, fmaf(-mA.y, i0, mA.x * r0)));
    IM[j].x = fmaf( mA.w, r1, fmaf(mA.z, i1, fmaf( mA.y, r0, mA.x * i0)));
    RE[j].y = fmaf( mA.y, i1, fmaf(mA.x, r1, fmaf(-mA.w, i0, -mA.z * r0)));
    IM[j].y = fmaf(-mA.y, r1, fmaf(mA.x, i1, fmaf( mA.w, r0, -mA.z * i0)));
  }
}

// --- CNOTs. new[i] = bitC(i) ? old[i ^ maskT] : old[i]
template <int GPOS, int LM>  // C lane, T lane
__device__ __forceinline__ void cnot_LL(v2f (&RE)[8], v2f (&IM)[8], int g) {
  const bool cb = (g >> GPOS) & 1;
#pragma unroll
  for (int j = 0; j < 8; ++j) {
    v2f pr = dpp2<LM>(RE[j]);
    v2f pi = dpp2<LM>(IM[j]);
    RE[j] = cb ? pr : RE[j];
    IM[j] = cb ? pi : IM[j];
  }
}
template <int GPOS, int JM>  // C lane, T reg j-bit
__device__ __forceinline__ void cnot_LR(v2f (&RE)[8], v2f (&IM)[8], int g) {
  const bool cb = (g >> GPOS) & 1;
#pragma unroll
  for (int j = 0; j < 8; ++j) {
    if (!(j & JM)) {
      const int j1 = j | JM;
      v2f r0 = RE[j], r1 = RE[j1];
      RE[j] = cb ? r1 : r0;  RE[j1] = cb ? r0 : r1;
      v2f i0 = IM[j], i1 = IM[j1];
      IM[j] = cb ? i1 : i0;  IM[j1] = cb ? i0 : i1;
    }
  }
}
template <int GPOS>  // C lane, T h
__device__ __forceinline__ void cnot_LH(v2f (&RE)[8], v2f (&IM)[8], int g) {
  const bool cb = (g >> GPOS) & 1;
#pragma unroll
  for (int j = 0; j < 8; ++j) {
    v2f r = RE[j]; v2f rs; rs.x = r.y; rs.y = r.x;
    RE[j] = cb ? rs : r;
    v2f i = IM[j]; v2f is2; is2.x = i.y; is2.y = i.x;
    IM[j] = cb ? is2 : i;
  }
}
template <int JC, int LM>  // C reg j-bit, T lane
__device__ __forceinline__ void cnot_RL(v2f (&RE)[8], v2f (&IM)[8]) {
#pragma unroll
  for (int j = 0; j < 8; ++j) {
    if (j & JC) {
      RE[j] = dpp2<LM>(RE[j]);
      IM[j] = dpp2<LM>(IM[j]);
    }
  }
}
template <int JC>  // C reg j-bit, T h
__device__ __forceinline__ void cnot_RH(v2f (&RE)[8], v2f (&IM)[8]) {
#pragma unroll
  for (int j = 0; j < 8; ++j) {
    if (j & JC) {
      v2f r = RE[j]; RE[j].x = r.y; RE[j].y = r.x;
      v2f i = IM[j]; IM[j].x = i.y; IM[j].y = i.x;
    }
  }
}
template <int LM>  // C h, T lane (only h=1 half moves)
__device__ __forceinline__ void cnot_HL(v2f (&RE)[8], v2f (&IM)[8]) {
#pragma unroll
  for (int j = 0; j < 8; ++j) {
    RE[j].y = lane_xor<LM>(RE[j].y);
    IM[j].y = lane_xor<LM>(IM[j].y);
  }
}
template <int JC, int JT>  // C reg, T reg: static swaps
__device__ __forceinline__ void cnot_RR(v2f (&RE)[8], v2f (&IM)[8]) {
#pragma unroll
  for (int j = 0; j < 8; ++j) {
    if ((j & JC) && !(j & JT)) {
      const int j1 = j | JT;
      v2f t = RE[j]; RE[j] = RE[j1]; RE[j1] = t;
      t = IM[j]; IM[j] = IM[j1]; IM[j1] = t;
    }
  }
}

__device__ __forceinline__ void stage_fence() { __threadfence_block(); }

__global__ __launch_bounds__(256) void hqc_kernel(
    const float* __restrict__ x,
    const float* __restrict__ w1, const float* __restrict__ b1,
    const float* __restrict__ w2, const float* __restrict__ b2,
    const float* __restrict__ w3, const float* __restrict__ b3,
    const float* __restrict__ qw,
    const float* __restrict__ wp1, const float* __restrict__ bp1,
    const float* __restrict__ wp2, const float* __restrict__ bp2,
    const float* __restrict__ wp3, const float* __restrict__ bp3,
    float* __restrict__ out, int B) {
  __shared__ __align__(16) float rotm[32][4];     // only m00r,m00i,m01r,m01i
  __shared__ float xbuf[16][44];
  __shared__ __align__(16) float hbuf[16][68];
  __shared__ float h2buf[16][34];
  __shared__ float qbuf[16][20];
  __shared__ float p1buf[16][34];
  __shared__ float p2buf[16][20];

  const int tid = threadIdx.x;
  const int g = tid & 15;
  const int ls = tid >> 4;
  const int s = blockIdx.x * 16 + ls;
  const bool valid = (s < B);

  // --- Rot coefficient setup: one thread per gate ---
  if (tid < 32) {
    float phi = qw[tid * 3 + 0];
    float th  = qw[tid * 3 + 1];
    float om  = qw[tid * 3 + 2];
    float st_, ct; sincosf(0.5f * th, &st_, &ct);
    float sa, ca;  sincosf(0.5f * (phi + om), &sa, &ca);
    float sb, cb;  sincosf(0.5f * (phi - om), &sb, &cb);
    rotm[tid][0] =  ca * ct;   // m00r
    rotm[tid][1] = -sa * ct;   // m00i
    rotm[tid][2] = -cb * st_;  // m01r
    rotm[tid][3] = -sb * st_;  // m01i
  }

  if (valid) {
    xbuf[ls][g]      = x[s * 41 + g];
    xbuf[ls][g + 16] = x[s * 41 + g + 16];
    if (g < 9) xbuf[ls][g + 32] = x[s * 41 + g + 32];
  }
  __syncthreads();

  // --- pre-MLP layer1: 41 -> 64 (packed) ---
  const float4* w1v = (const float4*)w1;  // [41][16]
  float4 bv = ((const float4*)b1)[g];
  v2f aA; aA.x = bv.x; aA.y = bv.y;
  v2f aB; aB.x = bv.z; aB.y = bv.w;
#pragma unroll 8
  for (int k = 0; k < 41; ++k) {
    float xk = xbuf[ls][k];
    float4 wv = w1v[k * 16 + g];
    v2f w01; w01.x = wv.x; w01.y = wv.y;
    v2f w23; w23.x = wv.z; w23.y = wv.w;
    v2f xv = sp(xk);
    aA = pkfma(xv, w01, aA);
    aB = pkfma(xv, w23, aB);
  }
  float4 st4;
  st4.x = fmaxf(aA.x, 0.f); st4.y = fmaxf(aA.y, 0.f);
  st4.z = fmaxf(aB.x, 0.f); st4.w = fmaxf(aB.y, 0.f);
  *(float4*)(&hbuf[ls][4 * g]) = st4;
  stage_fence();

  // --- layer2: 64 -> 32 (packed) ---
  const v2f* w2v = (const v2f*)w2;  // [64][16]
  v2f a2 = ((const v2f*)b2)[g];
#pragma unroll 8
  for (int k = 0; k < 64; ++k)
    a2 = pkfma(sp(hbuf[ls][k]), w2v[k * 16 + g], a2);
  h2buf[ls][2 * g]     = fmaxf(a2.x, 0.f);
  h2buf[ls][2 * g + 1] = fmaxf(a2.y, 0.f);
  stage_fence();

  // --- layer3: 32 -> 8, tanh, RY encoding ---
  if (g < 8) {
    float acc = b3[g];
#pragma unroll
    for (int k = 0; k < 32; ++k) acc = fmaf(h2buf[ls][k], w3[k * 8 + g], acc);
    float q = tanhf(acc);
    float sh, ch; sincosf(q * PI_HALF, &sh, &ch);
    qbuf[ls][g]     = ch;
    qbuf[ls][8 + g] = sh;
  }
  stage_fence();

  // --- init statevector ---
  float cwv[8], swv[8];
#pragma unroll
  for (int w = 0; w < 8; ++w) { cwv[w] = qbuf[ls][w]; swv[w] = qbuf[ls][8 + w]; }
  float lp = 1.0f;
#pragma unroll
  for (int w = 0; w < 4; ++w) lp *= ((g >> (3 - w)) & 1) ? swv[w] : cwv[w];
  float f45[4];
#pragma unroll
  for (int a = 0; a < 4; ++a)
    f45[a] = ((a & 2) ? swv[4] : cwv[4]) * ((a & 1) ? swv[5] : cwv[5]);
  v2f F67[2];
  F67[0].x = cwv[6] * cwv[7]; F67[0].y = cwv[6] * swv[7];
  F67[1].x = swv[6] * cwv[7]; F67[1].y = swv[6] * swv[7];
  v2f RE[8], IM[8];
#pragma unroll
  for (int j = 0; j < 8; ++j) {
    RE[j] = sp(lp * f45[j >> 1]) * F67[j & 1];
    IM[j] = sp(0.0f);
  }

#define RM(L, W) (*(const float4*)(&rotm[(L) * 8 + (W)][0]))
#define ROTS(L)                                 \
  rot_lane<0>(RE, IM, RM(L, 0), g);             \
  rot_lane<1>(RE, IM, RM(L, 1), g);             \
  rot_lane<2>(RE, IM, RM(L, 2), g);             \
  rot_lane<3>(RE, IM, RM(L, 3), g);             \
  rot_regj<4>(RE, IM, RM(L, 4));                \
  rot_regj<2>(RE, IM, RM(L, 5));                \
  rot_regj<1>(RE, IM, RM(L, 6));                \
  rot_regh(RE, IM, RM(L, 7));

  // layer 0, r=1: (0,1)(1,2)(2,3)(3,4)(4,5)(5,6)(6,7)(7,0)
  ROTS(0)
  cnot_LL<3, 4>(RE, IM, g);  cnot_LL<2, 2>(RE, IM, g);
  cnot_LL<1, 1>(RE, IM, g);  cnot_LR<0, 4>(RE, IM, g);
  cnot_RR<4, 2>(RE, IM);     cnot_RR<2, 1>(RE, IM);
  cnot_RH<1>(RE, IM);        cnot_HL<8>(RE, IM);
  // layer 1, r=2: (0,2)(1,3)(2,4)(3,5)(4,6)(5,7)(6,0)(7,1)
  ROTS(1)
  cnot_LL<3, 2>(RE, IM, g);  cnot_LL<2, 1>(RE, IM, g);
  cnot_LR<1, 4>(RE, IM, g);  cnot_LR<0, 2>(RE, IM, g);
  cnot_RR<4, 1>(RE, IM);     cnot_RH<2>(RE, IM);
  cnot_RL<1, 8>(RE, IM);     cnot_HL<4>(RE, IM);
  // layer 2, r=3: (0,3)(1,4)(2,5)(3,6)(4,7)(5,0)(6,1)(7,2)
  ROTS(2)
  cnot_LL<3, 1>(RE, IM, g);  cnot_LR<2, 4>(RE, IM, g);
  cnot_LR<1, 2>(RE, IM, g);  cnot_LR<0, 1>(RE, IM, g);
  cnot_RH<4>(RE, IM);        cnot_RL<2, 8>(RE, IM);
  cnot_RL<1, 4>(RE, IM);     cnot_HL<2>(RE, IM);
  // layer 3, r=4: (0,4)(1,5)(2,6)(3,7)(4,0)(5,1)(6,2)(7,3)
  ROTS(3)
  cnot_LR<3, 4>(RE, IM, g);  cnot_LR<2, 2>(RE, IM, g);
  cnot_LR<1, 1>(RE, IM, g);  cnot_LH<0>(RE, IM, g);
  cnot_RL<4, 8>(RE, IM);     cnot_RL<2, 4>(RE, IM);
  cnot_RL<1, 2>(RE, IM);     cnot_HL<1>(RE, IM);

  // --- expectations ---
  v2f pv[8];
#pragma unroll
  for (int j = 0; j < 8; ++j) pv[j] = pkfma(RE[j], RE[j], IM[j] * IM[j]);
  v2f t01 = pv[0] + pv[1], t23 = pv[2] + pv[3];
  v2f t45 = pv[4] + pv[5], t67 = pv[6] + pv[7];
  v2f tlo = t01 + t23, thi = t45 + t67;
  v2f tv = tlo + thi;
  float tot = tv.x + tv.y;
  float s4 = thi.x + thi.y;                       // q4: j bit2
  v2f v5 = t23 + t67; float s5 = v5.x + v5.y;     // q5: j bit1
  v2f v6 = (pv[1] + pv[3]) + (pv[5] + pv[7]);
  float s6 = v6.x + v6.y;                         // q6: j bit0
  float s7 = tv.y;                                // q7: h
  float zp[8];
  zp[0] = ((g >> 3) & 1) ? -tot : tot;
  zp[1] = ((g >> 2) & 1) ? -tot : tot;
  zp[2] = ((g >> 1) & 1) ? -tot : tot;
  zp[3] = (g & 1) ? -tot : tot;
  zp[4] = fmaf(-2.f, s4, tot);
  zp[5] = fmaf(-2.f, s5, tot);
  zp[6] = fmaf(-2.f, s6, tot);
  zp[7] = fmaf(-2.f, s7, tot);
#pragma unroll
  for (int w = 0; w < 8; ++w) zp[w] += lane_xor<1>(zp[w]);
#pragma unroll
  for (int w = 0; w < 8; ++w) zp[w] += lane_xor<2>(zp[w]);
#pragma unroll
  for (int w = 0; w < 8; ++w) zp[w] += lane_xor<4>(zp[w]);
#pragma unroll
  for (int w = 0; w < 8; ++w) zp[w] += lane_xor<8>(zp[w]);

  // --- post-MLP layer1: 8 -> 32 (packed) ---
  const v2f* wp1v = (const v2f*)wp1;  // [8][16]
  v2f q1 = ((const v2f*)bp1)[g];
#pragma unroll
  for (int k = 0; k < 8; ++k)
    q1 = pkfma(sp(zp[k]), wp1v[k * 16 + g], q1);
  p1buf[ls][2 * g]     = fmaxf(q1.x, 0.f);
  p1buf[ls][2 * g + 1] = fmaxf(q1.y, 0.f);
  stage_fence();

  // --- post layer2: 32 -> 16 ---
  float q2 = bp2[g];
#pragma unroll
  for (int k = 0; k < 32; ++k) q2 = fmaf(p1buf[ls][k], wp2[k * 16 + g], q2);
  p2buf[ls][g] = fmaxf(q2, 0.f);
  stage_fence();

  // --- post layer3: 16 -> 5 ---
  if (g < 5 && valid) {
    float o = bp3[g];
#pragma unroll
    for (int k = 0; k < 16; ++k) o = fmaf(p2buf[ls][k], wp3[k * 5 + g], o);
    out[s * 5 + g] = o;
  }
}

extern "C" void kernel_launch(void* const* d_in, const int* in_sizes, int n_in,
                              void* d_out, int out_size, void* d_ws,
                              size_t ws_size, hipStream_t stream) {
  const float* x   = (const float*)d_in[0];
  const float* w1  = (const float*)d_in[1];
  const float* b1  = (const float*)d_in[2];
  const float* w2  = (const float*)d_in[3];
  const float* b2  = (const float*)d_in[4];
  const float* w3  = (const float*)d_in[5];
  const float* b3  = (const float*)d_in[6];
  const float* qw  = (const float*)d_in[7];
  const float* wp1 = (const float*)d_in[8];
  const float* bp1 = (const float*)d_in[9];
  const float* wp2 = (const float*)d_in[10];
  const float* bp2 = (const float*)d_in[11];
  const float* wp3 = (const float*)d_in[12];
  const float* bp3 = (const float*)d_in[13];
  float* out = (float*)d_out;
  const int B = in_sizes[0] / 41;
  const int blocks = (B + 15) / 16;
  hipLaunchKernelGGL(hqc_kernel, dim3(blocks), dim3(256), 0, stream,
                     x, w1, b1, w2, b2, w3, b3, qw,
                     wp1, bp1, wp2, bp2, wp3, bp3, out, B);
}